// Round 1
// baseline (955.674 us; speedup 1.0000x reference)
//
#include <hip/hip_runtime.h>

// Dims fixed by the reference problem.
constexpr int B  = 8;
constexpr int S  = 2048;
constexpr int H  = 8192;
constexpr int R  = 16;

constexpr int HC = 512;   // h-chunk staged in LDS: 16 x 512 x 4B = 32 KiB
constexpr int G  = 4;     // s-rows per wave (acc regs = G*R = 64)
constexpr int ST = 16;    // s-rows per block = 4 waves * G

// out[b,s,r] = sum_h x[b,s,h] * weight[adapter_ids[b], r, h]
// Memory-bound on streaming x (512 MiB fp32). Weight staged via LDS,
// reused across G rows per lane to keep L2/LDS traffic off critical path.
__global__ __launch_bounds__(256, 4)
void multilora_einsum_kernel(const float* __restrict__ x,
                             const float* __restrict__ weight,
                             const int*   __restrict__ adapter_ids,
                             float*       __restrict__ out) {
    __shared__ __align__(16) float wlds[R * HC];   // 32 KiB

    const int t    = threadIdx.x;
    const int lane = t & 63;
    const int wv   = t >> 6;            // wave id 0..3
    const int blk  = blockIdx.x;
    const int b    = blk & 7;           // batch -> XCD-friendly round robin
    const int tile = blk >> 3;          // 0..127 s-tiles per batch
    const int s0   = tile * ST + wv * G;

    const int aid = adapter_ids[b];
    const float* wbase = weight + (size_t)aid * (R * H);

    // per-row x base pointers
    const float* xrow[G];
#pragma unroll
    for (int g = 0; g < G; ++g)
        xrow[g] = x + (size_t)(b * S + s0 + g) * H;

    float acc[G][R];
#pragma unroll
    for (int g = 0; g < G; ++g)
#pragma unroll
        for (int r = 0; r < R; ++r)
            acc[g][r] = 0.0f;

    const float4* wlds4 = (const float4*)wlds;
    float4*       wdst4 = (float4*)wlds;

    for (int c = 0; c < H / HC; ++c) {
        const int h0 = c * HC;

        // ---- stage weight chunk [R x HC] into LDS, fully coalesced ----
        // R*HC/4 = 2048 float4s, 256 threads -> 8 each
#pragma unroll
        for (int k = 0; k < (R * HC / 4) / 256; ++k) {
            const int f  = t + 256 * k;
            const int r  = f >> 7;        // / (HC/4)
            const int hh = f & 127;       // % (HC/4)
            wdst4[f] = ((const float4*)(wbase + (size_t)r * H + h0))[hh];
        }
        __syncthreads();

        // ---- compute: lanes split h (stride 256 floats per j) ----
#pragma unroll
        for (int j = 0; j < HC / 256; ++j) {
            const int hl = 4 * lane + 256 * j;  // float offset within chunk

            float4 xv[G];
#pragma unroll
            for (int g = 0; g < G; ++g)
                xv[g] = *(const float4*)(xrow[g] + h0 + hl);

#pragma unroll
            for (int r = 0; r < R; ++r) {
                const float4 w4 = wlds4[r * (HC / 4) + lane + 64 * j];
#pragma unroll
                for (int g = 0; g < G; ++g) {
                    acc[g][r] = fmaf(xv[g].x, w4.x, acc[g][r]);
                    acc[g][r] = fmaf(xv[g].y, w4.y, acc[g][r]);
                    acc[g][r] = fmaf(xv[g].z, w4.z, acc[g][r]);
                    acc[g][r] = fmaf(xv[g].w, w4.w, acc[g][r]);
                }
            }
        }
        __syncthreads();
    }

    // ---- cross-lane reduce (each lane holds a partial over its h subset) ----
#pragma unroll
    for (int g = 0; g < G; ++g) {
#pragma unroll
        for (int r = 0; r < R; ++r) {
            float v = acc[g][r];
#pragma unroll
            for (int off = 32; off > 0; off >>= 1)
                v += __shfl_down(v, off, 64);
            if (lane == 0)
                out[(size_t)(b * S + s0 + g) * R + r] = v;
        }
    }
}

extern "C" void kernel_launch(void* const* d_in, const int* in_sizes, int n_in,
                              void* d_out, int out_size, void* d_ws, size_t ws_size,
                              hipStream_t stream) {
    const float* x           = (const float*)d_in[0];  // [B,S,H]
    const float* weight      = (const float*)d_in[1];  // [MAX_LORAS,R,H]
    // d_in[2] = weight_active: fully overwritten by the gather in the
    // reference before use -> output does not depend on it; ignored.
    const int*   adapter_ids = (const int*)d_in[3];    // [B]
    float*       out         = (float*)d_out;          // [B,S,R] fp32

    const int nblocks = B * (S / ST);  // 1024
    multilora_einsum_kernel<<<nblocks, 256, 0, stream>>>(x, weight, adapter_ids, out);
}